// Round 1
// baseline (449.915 us; speedup 1.0000x reference)
//
#include <hip/hip_runtime.h>
#include <hip/hip_bf16.h>
#include <stdint.h>

// ---------------------------------------------------------------------------
// TernaryExpert: out = TL(gelu(TL(x, w_up)), w_down)
//   TL(x,w) = rmsnorm(x) @ ternary(w)^T
// Sizes: x [4,4096,1024] f32; w_up [4096,1024] f32; w_down [1024,4096] f32
// M = 16384, d_model = 1024, d_ff = 4096. Output f32 [16384,1024].
// ---------------------------------------------------------------------------

#define M_ROWS   16384
#define D_MODEL  1024
#define D_FF     4096
#define NW       (D_FF * D_MODEL)   // 4194304 elements per weight matrix

typedef __attribute__((ext_vector_type(8))) short bf16x8;
typedef __attribute__((ext_vector_type(4))) float f32x4;
typedef __attribute__((ext_vector_type(8))) unsigned short u16x8;

__device__ __forceinline__ unsigned short f2bf(float f) {
    unsigned u = __builtin_bit_cast(unsigned, f);
    u += 0x7FFFu + ((u >> 16) & 1u);          // RNE
    return (unsigned short)(u >> 16);
}
__device__ __forceinline__ float bf2f(unsigned short h) {
    return __builtin_bit_cast(float, ((unsigned)h) << 16);
}

__device__ __forceinline__ void gload_lds16(const void* g, void* l) {
    __builtin_amdgcn_global_load_lds(
        (const __attribute__((address_space(1))) void*)g,
        (__attribute__((address_space(3))) void*)l, 16, 0, 0);
}

// ---------------------------------------------------------------------------
// 1) sum(|w|) reduction -> double atomic
// ---------------------------------------------------------------------------
__global__ __launch_bounds__(256) void absmean_reduce(const float* __restrict__ w,
                                                      double* __restrict__ asum) {
    const int n4 = NW / 4;
    float s = 0.f;
    const float4* w4 = (const float4*)w;
    for (int i = blockIdx.x * blockDim.x + threadIdx.x; i < n4;
         i += gridDim.x * blockDim.x) {
        float4 v = w4[i];
        s += fabsf(v.x) + fabsf(v.y) + fabsf(v.z) + fabsf(v.w);
    }
    #pragma unroll
    for (int off = 32; off > 0; off >>= 1) s += __shfl_down(s, off);
    __shared__ float sm[4];
    int lane = threadIdx.x & 63, wid = threadIdx.x >> 6;
    if (lane == 0) sm[wid] = s;
    __syncthreads();
    if (threadIdx.x == 0) {
        float t = sm[0] + sm[1] + sm[2] + sm[3];
        atomicAdd(asum, (double)t);
    }
}

// ---------------------------------------------------------------------------
// 2) ternarize: wq = bf16(sign(w) * (|w| > 0.5*mean|w|))
// ---------------------------------------------------------------------------
__global__ __launch_bounds__(256) void quant_kernel(const float* __restrict__ w,
                                                    const double* __restrict__ asum,
                                                    unsigned short* __restrict__ wq) {
    float thr = (float)(0.5 * (*asum) * (1.0 / (double)NW));
    int i = blockIdx.x * blockDim.x + threadIdx.x;   // one float4 per thread
    float4 v = ((const float4*)w)[i];
    ushort4 o;
    o.x = (fabsf(v.x) > thr) ? (v.x > 0.f ? 0x3F80 : 0xBF80) : 0;
    o.y = (fabsf(v.y) > thr) ? (v.y > 0.f ? 0x3F80 : 0xBF80) : 0;
    o.z = (fabsf(v.z) > thr) ? (v.z > 0.f ? 0x3F80 : 0xBF80) : 0;
    o.w = (fabsf(v.w) > thr) ? (v.w > 0.f ? 0x3F80 : 0xBF80) : 0;
    ((ushort4*)wq)[i] = o;
}

// ---------------------------------------------------------------------------
// 3) rmsnorm of x (d=1024): one block per row, 256 thr x float4
// ---------------------------------------------------------------------------
__global__ __launch_bounds__(256) void rmsnorm_x(const float* __restrict__ x,
                                                 unsigned short* __restrict__ xn) {
    const int row = blockIdx.x;
    const float4* xr = (const float4*)(x + (size_t)row * D_MODEL);
    float4 v = xr[threadIdx.x];
    float ss = v.x * v.x + v.y * v.y + v.z * v.z + v.w * v.w;
    #pragma unroll
    for (int off = 32; off > 0; off >>= 1) ss += __shfl_down(ss, off);
    __shared__ float sm[4];
    int lane = threadIdx.x & 63, wid = threadIdx.x >> 6;
    if (lane == 0) sm[wid] = ss;
    __syncthreads();
    float tot = sm[0] + sm[1] + sm[2] + sm[3];
    float s = 1.0f / (sqrtf(tot) * (1.0f / 32.0f) + 1e-8f);  // sqrt(1024)=32
    ushort4 o;
    o.x = f2bf(v.x * s); o.y = f2bf(v.y * s);
    o.z = f2bf(v.z * s); o.w = f2bf(v.w * s);
    ((ushort4*)(xn + (size_t)row * D_MODEL))[threadIdx.x] = o;
}

// ---------------------------------------------------------------------------
// 4) row scales of h (d=4096): one block per row, 256 thr x 16 bf16
// ---------------------------------------------------------------------------
__global__ __launch_bounds__(256) void rowscale_h(const unsigned short* __restrict__ h,
                                                  float* __restrict__ rs) {
    const int row = blockIdx.x;
    const u16x8* hr = (const u16x8*)(h + (size_t)row * D_FF);
    u16x8 a = hr[threadIdx.x * 2 + 0];
    u16x8 b = hr[threadIdx.x * 2 + 1];
    float ss = 0.f;
    #pragma unroll
    for (int j = 0; j < 8; ++j) { float f = bf2f(a[j]); ss += f * f; }
    #pragma unroll
    for (int j = 0; j < 8; ++j) { float f = bf2f(b[j]); ss += f * f; }
    #pragma unroll
    for (int off = 32; off > 0; off >>= 1) ss += __shfl_down(ss, off);
    __shared__ float sm[4];
    int lane = threadIdx.x & 63, wid = threadIdx.x >> 6;
    if (lane == 0) sm[wid] = ss;
    __syncthreads();
    if (threadIdx.x == 0) {
        float tot = sm[0] + sm[1] + sm[2] + sm[3];
        rs[row] = 1.0f / (sqrtf(tot) * (1.0f / 64.0f) + 1e-8f);  // sqrt(4096)=64
    }
}

// ---------------------------------------------------------------------------
// 5) GEMM (both operands K-contiguous): C[m][n] = sum_k A[m,k]*B[n,k]
//    128x128 tile, BK=64, 4 waves (2x2 of 64x64), 16x16x32 bf16 MFMA.
//    global_load_lds width 16 with pre-swizzled source; XOR-swizzled ds_read.
//    EPI=0: C = bf16(gelu(acc)) -> Cbf;  EPI=1: C = acc*rowscale[m] -> Cf.
// ---------------------------------------------------------------------------
template <int EPI>
__global__ __launch_bounds__(256) void gemm_bt(const unsigned short* __restrict__ A,
                                               const unsigned short* __restrict__ B,
                                               unsigned short* __restrict__ Cbf,
                                               float* __restrict__ Cf,
                                               const float* __restrict__ rowscale,
                                               int M, int N, int K) {
    __shared__ unsigned short As[128 * 64];
    __shared__ unsigned short Bs[128 * 64];

    const int tid  = threadIdx.x;
    const int lane = tid & 63;
    const int wid  = tid >> 6;
    const int wr   = wid >> 1;      // 0..1
    const int wc   = wid & 1;       // 0..1
    const int m0   = blockIdx.y * 128;
    const int n0   = blockIdx.x * 128;

    const int lr = lane & 15;       // row within 16-frag
    const int lk = lane >> 4;       // k-group 0..3

    f32x4 acc[4][4];
    #pragma unroll
    for (int mi = 0; mi < 4; ++mi)
        #pragma unroll
        for (int ni = 0; ni < 4; ++ni)
            acc[mi][ni] = (f32x4){0.f, 0.f, 0.f, 0.f};

    // staging geometry (per thread): 4 insts x 16B each for A and B
    const int sr = tid >> 3;             // 0..31 (row sub-block)
    const int sq = (tid & 7) * 16;       // byte col within row (0..112)

    for (int k0 = 0; k0 < K; k0 += 64) {
        #pragma unroll
        for (int inst = 0; inst < 4; ++inst) {
            int r  = inst * 32 + sr;                 // tile row 0..127
            int qs = sq ^ ((r & 7) << 4);            // pre-swizzled source byte col
            gload_lds16(A + (size_t)(m0 + r) * K + k0 + (qs >> 1),
                        &As[inst * 2048 + tid * 8]);
            gload_lds16(B + (size_t)(n0 + r) * K + k0 + (qs >> 1),
                        &Bs[inst * 2048 + tid * 8]);
        }
        __syncthreads();

        #pragma unroll
        for (int kk = 0; kk < 2; ++kk) {
            const int kbyte = kk * 64 + lk * 16;
            bf16x8 av[4], bv[4];
            #pragma unroll
            for (int mi = 0; mi < 4; ++mi) {
                int r = wr * 64 + mi * 16 + lr;
                av[mi] = *(const bf16x8*)((const char*)As + r * 128 +
                                          (kbyte ^ ((r & 7) << 4)));
            }
            #pragma unroll
            for (int ni = 0; ni < 4; ++ni) {
                int r = wc * 64 + ni * 16 + lr;
                bv[ni] = *(const bf16x8*)((const char*)Bs + r * 128 +
                                          (kbyte ^ ((r & 7) << 4)));
            }
            #pragma unroll
            for (int mi = 0; mi < 4; ++mi)
                #pragma unroll
                for (int ni = 0; ni < 4; ++ni)
                    acc[mi][ni] = __builtin_amdgcn_mfma_f32_16x16x32_bf16(
                        av[mi], bv[ni], acc[mi][ni], 0, 0, 0);
        }
        __syncthreads();
    }

    // epilogue: C/D frag mapping col = lane&15, row = (lane>>4)*4 + reg
    #pragma unroll
    for (int mi = 0; mi < 4; ++mi) {
        #pragma unroll
        for (int j = 0; j < 4; ++j) {
            int gr = m0 + wr * 64 + mi * 16 + lk * 4 + j;
            float s = 0.f;
            if (EPI == 1) s = rowscale[gr];
            #pragma unroll
            for (int ni = 0; ni < 4; ++ni) {
                int gc = n0 + wc * 64 + ni * 16 + lr;
                float v = acc[mi][ni][j];
                if (EPI == 0) {
                    float g = 0.5f * v * (1.0f + erff(v * 0.70710678118654752f));
                    Cbf[(size_t)gr * N + gc] = f2bf(g);
                } else {
                    Cf[(size_t)gr * N + gc] = v * s;
                }
            }
        }
    }
}

// ---------------------------------------------------------------------------
extern "C" void kernel_launch(void* const* d_in, const int* in_sizes, int n_in,
                              void* d_out, int out_size, void* d_ws, size_t ws_size,
                              hipStream_t stream) {
    const float* x    = (const float*)d_in[0];
    const float* w_up = (const float*)d_in[1];
    const float* w_dn = (const float*)d_in[2];
    float* out = (float*)d_out;

    uint8_t* ws = (uint8_t*)d_ws;
    unsigned short* h   = (unsigned short*)(ws);                       // 128 MB
    unsigned short* xn  = (unsigned short*)(ws + 134217728);           // 32 MB
    unsigned short* wqu = (unsigned short*)(ws + 134217728 + 33554432);          // 8 MB
    unsigned short* wqd = (unsigned short*)(ws + 134217728 + 33554432 + 8388608); // 8 MB
    float*  rs   = (float*)(ws + 134217728 + 33554432 + 2 * 8388608);  // 64 KB
    double* alph = (double*)(ws + 134217728 + 33554432 + 2 * 8388608 + 65536);

    hipMemsetAsync(alph, 0, 16, stream);

    absmean_reduce<<<256, 256, 0, stream>>>(w_up, alph + 0);
    absmean_reduce<<<256, 256, 0, stream>>>(w_dn, alph + 1);
    quant_kernel<<<NW / 1024, 256, 0, stream>>>(w_up, alph + 0, wqu);
    quant_kernel<<<NW / 1024, 256, 0, stream>>>(w_dn, alph + 1, wqd);
    rmsnorm_x<<<M_ROWS, 256, 0, stream>>>(x, xn);

    // L1: h = gelu(xn @ wqu^T)   [16384 x 4096], K=1024
    gemm_bt<0><<<dim3(D_FF / 128, M_ROWS / 128), 256, 0, stream>>>(
        xn, wqu, h, nullptr, nullptr, M_ROWS, D_FF, D_MODEL);

    rowscale_h<<<M_ROWS, 256, 0, stream>>>(h, rs);

    // L2: out = (h @ wqd^T) * rs[m]   [16384 x 1024], K=4096
    gemm_bt<1><<<dim3(D_MODEL / 128, M_ROWS / 128), 256, 0, stream>>>(
        h, wqd, nullptr, out, rs, M_ROWS, D_MODEL, D_FF);
}

// Round 2
// 370.077 us; speedup vs baseline: 1.2157x; 1.2157x over previous
//
#include <hip/hip_runtime.h>
#include <hip/hip_bf16.h>
#include <stdint.h>

// ---------------------------------------------------------------------------
// TernaryExpert: out = TL(gelu(TL(x, w_up)), w_down)
//   TL(x,w) = rmsnorm(x) @ ternary(w)^T
// M = 16384, d_model = 1024, d_ff = 4096. Output f32 [16384,1024].
// GEMM: 256x128 tile, BK=64, 8 waves, 8-phase-style counted-vmcnt schedule,
// triple-buffered LDS (race-free counted waits), XOR-swizzled LDS.
// ---------------------------------------------------------------------------

#define M_ROWS   16384
#define D_MODEL  1024
#define D_FF     4096
#define NW       (D_FF * D_MODEL)

typedef __attribute__((ext_vector_type(8))) short bf16x8;
typedef __attribute__((ext_vector_type(4))) float f32x4;
typedef __attribute__((ext_vector_type(8))) unsigned short u16x8;

__device__ __forceinline__ unsigned short f2bf(float f) {
    unsigned u = __builtin_bit_cast(unsigned, f);
    u += 0x7FFFu + ((u >> 16) & 1u);          // RNE
    return (unsigned short)(u >> 16);
}
__device__ __forceinline__ float bf2f(unsigned short h) {
    return __builtin_bit_cast(float, ((unsigned)h) << 16);
}

__device__ __forceinline__ void gload_lds16(const void* g, void* l) {
    __builtin_amdgcn_global_load_lds(
        (const __attribute__((address_space(1))) void*)g,
        (__attribute__((address_space(3))) void*)l, 16, 0, 0);
}

__device__ __forceinline__ void barrier_raw() {
    asm volatile("" ::: "memory");
    __builtin_amdgcn_sched_barrier(0);
    __builtin_amdgcn_s_barrier();
    __builtin_amdgcn_sched_barrier(0);
    asm volatile("" ::: "memory");
}

#define LGKM0() do { asm volatile("s_waitcnt lgkmcnt(0)" ::: "memory"); \
                     __builtin_amdgcn_sched_barrier(0); } while (0)
#define VMCNT6() do { asm volatile("s_waitcnt vmcnt(6)" ::: "memory"); \
                      __builtin_amdgcn_sched_barrier(0); } while (0)

__device__ __forceinline__ float gelu_fast(float v) {
    // 0.5*v*(1+tanh(y)) == v*sigmoid(2y), y = sqrt(2/pi)*(v + 0.044715 v^3)
    float w = v * v;
    float z = v * __builtin_fmaf(w, 0.07135481627f, 1.5957691216f);
    float e = __expf(-z);
    return v / (1.0f + e);
}

// ---------------------------------------------------------------------------
// aux kernels (unchanged from round 1)
// ---------------------------------------------------------------------------
__global__ __launch_bounds__(256) void absmean_reduce(const float* __restrict__ w,
                                                      double* __restrict__ asum) {
    const int n4 = NW / 4;
    float s = 0.f;
    const float4* w4 = (const float4*)w;
    for (int i = blockIdx.x * blockDim.x + threadIdx.x; i < n4;
         i += gridDim.x * blockDim.x) {
        float4 v = w4[i];
        s += fabsf(v.x) + fabsf(v.y) + fabsf(v.z) + fabsf(v.w);
    }
    #pragma unroll
    for (int off = 32; off > 0; off >>= 1) s += __shfl_down(s, off);
    __shared__ float sm[4];
    int lane = threadIdx.x & 63, wid = threadIdx.x >> 6;
    if (lane == 0) sm[wid] = s;
    __syncthreads();
    if (threadIdx.x == 0) {
        float t = sm[0] + sm[1] + sm[2] + sm[3];
        atomicAdd(asum, (double)t);
    }
}

__global__ __launch_bounds__(256) void quant_kernel(const float* __restrict__ w,
                                                    const double* __restrict__ asum,
                                                    unsigned short* __restrict__ wq) {
    float thr = (float)(0.5 * (*asum) * (1.0 / (double)NW));
    int i = blockIdx.x * blockDim.x + threadIdx.x;
    float4 v = ((const float4*)w)[i];
    ushort4 o;
    o.x = (fabsf(v.x) > thr) ? (v.x > 0.f ? 0x3F80 : 0xBF80) : 0;
    o.y = (fabsf(v.y) > thr) ? (v.y > 0.f ? 0x3F80 : 0xBF80) : 0;
    o.z = (fabsf(v.z) > thr) ? (v.z > 0.f ? 0x3F80 : 0xBF80) : 0;
    o.w = (fabsf(v.w) > thr) ? (v.w > 0.f ? 0x3F80 : 0xBF80) : 0;
    ((ushort4*)wq)[i] = o;
}

__global__ __launch_bounds__(256) void rmsnorm_x(const float* __restrict__ x,
                                                 unsigned short* __restrict__ xn) {
    const int row = blockIdx.x;
    const float4* xr = (const float4*)(x + (size_t)row * D_MODEL);
    float4 v = xr[threadIdx.x];
    float ss = v.x * v.x + v.y * v.y + v.z * v.z + v.w * v.w;
    #pragma unroll
    for (int off = 32; off > 0; off >>= 1) ss += __shfl_down(ss, off);
    __shared__ float sm[4];
    int lane = threadIdx.x & 63, wid = threadIdx.x >> 6;
    if (lane == 0) sm[wid] = ss;
    __syncthreads();
    float tot = sm[0] + sm[1] + sm[2] + sm[3];
    float s = 1.0f / (sqrtf(tot) * (1.0f / 32.0f) + 1e-8f);
    ushort4 o;
    o.x = f2bf(v.x * s); o.y = f2bf(v.y * s);
    o.z = f2bf(v.z * s); o.w = f2bf(v.w * s);
    ((ushort4*)(xn + (size_t)row * D_MODEL))[threadIdx.x] = o;
}

__global__ __launch_bounds__(256) void rowscale_h(const unsigned short* __restrict__ h,
                                                  float* __restrict__ rs) {
    const int row = blockIdx.x;
    const u16x8* hr = (const u16x8*)(h + (size_t)row * D_FF);
    u16x8 a = hr[threadIdx.x * 2 + 0];
    u16x8 b = hr[threadIdx.x * 2 + 1];
    float ss = 0.f;
    #pragma unroll
    for (int j = 0; j < 8; ++j) { float f = bf2f(a[j]); ss += f * f; }
    #pragma unroll
    for (int j = 0; j < 8; ++j) { float f = bf2f(b[j]); ss += f * f; }
    #pragma unroll
    for (int off = 32; off > 0; off >>= 1) ss += __shfl_down(ss, off);
    __shared__ float sm[4];
    int lane = threadIdx.x & 63, wid = threadIdx.x >> 6;
    if (lane == 0) sm[wid] = ss;
    __syncthreads();
    if (threadIdx.x == 0) {
        float tot = sm[0] + sm[1] + sm[2] + sm[3];
        rs[row] = 1.0f / (sqrtf(tot) * (1.0f / 64.0f) + 1e-8f);
    }
}

// ---------------------------------------------------------------------------
// GEMM: C[m][n] = sum_k A[m,k]*B[n,k]   (both K-contiguous)
// BM=256 BN=128 BK=64, 512 thr (8 waves: 4M x 2N, 64x64 per wave).
// LDS: 3 buffers x (A 32KB + B 16KB) = 144KB. Compute t from buf[t%3],
// stage t+2 into buf[(t+2)%3]; vmcnt(6) at K-tile end => t+1 landed,
// t+2's 6 loads still in flight (never drains to 0).
// ---------------------------------------------------------------------------
template <int EPI, int KDIM, int NBLKN>
__global__ __launch_bounds__(512, 1) void gemm8p(const unsigned short* __restrict__ A,
                                                 const unsigned short* __restrict__ B,
                                                 unsigned short* __restrict__ Cbf,
                                                 float* __restrict__ Cf,
                                                 const float* __restrict__ rowscale,
                                                 int nwg) {
    constexpr int BUFB = 49152;                 // 48KB per K-tile buffer
    constexpr int NT = KDIM / 64;
    __shared__ char smem[3 * BUFB];

    const int tid = threadIdx.x;
    // XCD-aware block swizzle (nwg % 8 == 0 for both GEMMs)
    const int bid = blockIdx.x;
    const int swz = (bid & 7) * (nwg >> 3) + (bid >> 3);
    const uint m0 = (uint)(swz / NBLKN) * 256u;
    const uint n0 = (uint)(swz % NBLKN) * 128u;

    const int lane = tid & 63;
    const int wid  = tid >> 6;
    const int wm   = wid >> 1;                  // 0..3 -> 64-row slice
    const int wn   = wid & 1;                   // 0..1 -> 64-col slice
    const int lr   = lane & 15;
    const int lk   = lane >> 4;

    // staging geometry: thread covers row (tid>>3), 16B chunk (tid&7), pre-swizzled
    const uint rowBase = (uint)(tid >> 3);                       // 0..63
    const uint colE = (((uint)(tid & 7) << 4) ^ ((rowBase & 7u) << 4)) >> 1;
    const uint aBase = (m0 + rowBase) * (uint)KDIM + colE;
    const uint bBase = (n0 + rowBase) * (uint)KDIM + colE;
    const uint dstOff = (uint)tid * 16u;

    // fragment read offsets (byte), same XOR involution as staging
    const uint xorv = ((uint)(lr & 7)) << 4;
    const uint kb0 = (((uint)lk << 4)       ) ^ xorv;
    const uint kb1 = (((uint)lk << 4) | 64u ) ^ xorv;
    uint offAm[4], offBn[4];
    #pragma unroll
    for (int i = 0; i < 4; ++i) {
        offAm[i] = (uint)(wm * 64 + i * 16 + lr) * 128u;
        offBn[i] = 32768u + (uint)(wn * 64 + i * 16 + lr) * 128u;
    }

    f32x4 acc[4][4];
    #pragma unroll
    for (int mi = 0; mi < 4; ++mi)
        #pragma unroll
        for (int ni = 0; ni < 4; ++ni)
            acc[mi][ni] = (f32x4){0.f, 0.f, 0.f, 0.f};

    // prologue: stage K-tiles 0 and 1
    #pragma unroll
    for (int t = 0; t < 2; ++t) {
        char* sb = smem + t * BUFB;
        #pragma unroll
        for (int i = 0; i < 4; ++i)
            gload_lds16(A + aBase + (uint)i * 64u * KDIM + (uint)t * 64u,
                        sb + i * 8192 + dstOff);
        #pragma unroll
        for (int i = 0; i < 2; ++i)
            gload_lds16(B + bBase + (uint)i * 64u * KDIM + (uint)t * 64u,
                        sb + 32768 + i * 8192 + dstOff);
    }
    VMCNT6();
    barrier_raw();

    int cbuf = 0, sbuf = 2;
    #pragma unroll 1
    for (int t = 0; t < NT; ++t) {
        const char* cA = smem + cbuf * BUFB;
        char* sb = smem + sbuf * BUFB;
        const uint t2 = (uint)(t + 2) * 64u;
        const bool doStage = (t + 2 < NT);
        bf16x8 av[4], bv[4];

        // ---- phase 1 (kk0) ----
        #pragma unroll
        for (int i = 0; i < 4; ++i) av[i] = *(const bf16x8*)(cA + offAm[i] + kb0);
        #pragma unroll
        for (int i = 0; i < 4; ++i) bv[i] = *(const bf16x8*)(cA + offBn[i] + kb0);
        if (doStage) {
            gload_lds16(A + aBase + 0u * (uint)KDIM + t2, sb + 0 * 8192 + dstOff);
            gload_lds16(A + aBase + 64u * (uint)KDIM + t2, sb + 1 * 8192 + dstOff);
            gload_lds16(B + bBase + 0u * (uint)KDIM + t2, sb + 32768 + dstOff);
        }
        barrier_raw();
        LGKM0();
        __builtin_amdgcn_s_setprio(1);
        #pragma unroll
        for (int mi = 0; mi < 4; ++mi)
            #pragma unroll
            for (int ni = 0; ni < 4; ++ni)
                acc[mi][ni] = __builtin_amdgcn_mfma_f32_16x16x32_bf16(
                    av[mi], bv[ni], acc[mi][ni], 0, 0, 0);
        __builtin_amdgcn_s_setprio(0);
        barrier_raw();

        // ---- phase 2 (kk1) ----
        #pragma unroll
        for (int i = 0; i < 4; ++i) av[i] = *(const bf16x8*)(cA + offAm[i] + kb1);
        #pragma unroll
        for (int i = 0; i < 4; ++i) bv[i] = *(const bf16x8*)(cA + offBn[i] + kb1);
        if (doStage) {
            gload_lds16(A + aBase + 128u * (uint)KDIM + t2, sb + 2 * 8192 + dstOff);
            gload_lds16(A + aBase + 192u * (uint)KDIM + t2, sb + 3 * 8192 + dstOff);
            gload_lds16(B + bBase + 64u * (uint)KDIM + t2, sb + 32768 + 8192 + dstOff);
        }
        barrier_raw();
        LGKM0();
        __builtin_amdgcn_s_setprio(1);
        #pragma unroll
        for (int mi = 0; mi < 4; ++mi)
            #pragma unroll
            for (int ni = 0; ni < 4; ++ni)
                acc[mi][ni] = __builtin_amdgcn_mfma_f32_16x16x32_bf16(
                    av[mi], bv[ni], acc[mi][ni], 0, 0, 0);
        __builtin_amdgcn_s_setprio(0);
        VMCNT6();
        barrier_raw();

        cbuf = (cbuf == 2) ? 0 : cbuf + 1;
        sbuf = (sbuf == 2) ? 0 : sbuf + 1;
    }

    // epilogue: C/D frag mapping col = lane&15, row = (lane>>4)*4 + reg
    constexpr uint N = (uint)NBLKN * 128u;
    #pragma unroll
    for (int mi = 0; mi < 4; ++mi) {
        #pragma unroll
        for (int j = 0; j < 4; ++j) {
            const uint gr = m0 + (uint)(wm * 64 + mi * 16 + lk * 4 + j);
            float s = 0.f;
            if (EPI == 1) s = rowscale[gr];
            #pragma unroll
            for (int ni = 0; ni < 4; ++ni) {
                const uint gc = n0 + (uint)(wn * 64 + ni * 16 + lr);
                float v = acc[mi][ni][j];
                if (EPI == 0) {
                    Cbf[gr * N + gc] = f2bf(gelu_fast(v));
                } else {
                    Cf[gr * N + gc] = v * s;
                }
            }
        }
    }
}

// ---------------------------------------------------------------------------
extern "C" void kernel_launch(void* const* d_in, const int* in_sizes, int n_in,
                              void* d_out, int out_size, void* d_ws, size_t ws_size,
                              hipStream_t stream) {
    const float* x    = (const float*)d_in[0];
    const float* w_up = (const float*)d_in[1];
    const float* w_dn = (const float*)d_in[2];
    float* out = (float*)d_out;

    uint8_t* ws = (uint8_t*)d_ws;
    unsigned short* h   = (unsigned short*)(ws);                       // 128 MB
    unsigned short* xn  = (unsigned short*)(ws + 134217728);           // 32 MB
    unsigned short* wqu = (unsigned short*)(ws + 134217728 + 33554432);
    unsigned short* wqd = (unsigned short*)(ws + 134217728 + 33554432 + 8388608);
    float*  rs   = (float*)(ws + 134217728 + 33554432 + 2 * 8388608);
    double* alph = (double*)(ws + 134217728 + 33554432 + 2 * 8388608 + 65536);

    hipMemsetAsync(alph, 0, 16, stream);

    absmean_reduce<<<256, 256, 0, stream>>>(w_up, alph + 0);
    absmean_reduce<<<256, 256, 0, stream>>>(w_dn, alph + 1);
    quant_kernel<<<NW / 1024, 256, 0, stream>>>(w_up, alph + 0, wqu);
    quant_kernel<<<NW / 1024, 256, 0, stream>>>(w_dn, alph + 1, wqd);
    rmsnorm_x<<<M_ROWS, 256, 0, stream>>>(x, xn);

    // L1: h = gelu(xn @ wqu^T)   [16384 x 4096], K=1024 -> 64x32 = 2048 blocks
    gemm8p<0, D_MODEL, 32><<<2048, 512, 0, stream>>>(
        xn, wqu, h, nullptr, nullptr, 2048);

    rowscale_h<<<M_ROWS, 256, 0, stream>>>(h, rs);

    // L2: out = (h @ wqd^T) * rs[m]   [16384 x 1024], K=4096 -> 64x8 = 512 blocks
    gemm8p<1, D_FF, 8><<<512, 512, 0, stream>>>(
        h, wqd, nullptr, out, rs, 512);
}

// Round 4
// 336.944 us; speedup vs baseline: 1.3353x; 1.0983x over previous
//
#include <hip/hip_runtime.h>
#include <hip/hip_bf16.h>
#include <stdint.h>

// ---------------------------------------------------------------------------
// TernaryExpert: out = TL(gelu(TL(x, w_up)), w_down)
//   TL(x,w) = rmsnorm(x) @ ternary(w)^T
// M = 16384, d_model = 1024, d_ff = 4096. Output f32 [16384,1024].
// GEMM: 256x256 tile, BK=64, 8 waves (2Mx4N, 128x64/wave), 4-phase K-tile
// schedule with counted vmcnt, double-buffered 128KB LDS, XOR-swizzled LDS.
// Staging issued in NEED order: {B0..B3} ph0/ph1, {A0,A2} ph2, {A1,A3} ph3,
// so vmcnt(2) at tile boundary leaves exactly the phase-1-needed quarters
// in flight (round-3 race fix: A2 was issued after A1 but needed at ph0).
// ---------------------------------------------------------------------------

#define M_ROWS   16384
#define D_MODEL  1024
#define D_FF     4096
#define NW       (D_FF * D_MODEL)

typedef __attribute__((ext_vector_type(8))) short bf16x8;
typedef __attribute__((ext_vector_type(4))) float f32x4;
typedef __attribute__((ext_vector_type(8))) unsigned short u16x8;

__device__ __forceinline__ unsigned short f2bf(float f) {
    unsigned u = __builtin_bit_cast(unsigned, f);
    u += 0x7FFFu + ((u >> 16) & 1u);          // RNE
    return (unsigned short)(u >> 16);
}
__device__ __forceinline__ float bf2f(unsigned short h) {
    return __builtin_bit_cast(float, ((unsigned)h) << 16);
}

__device__ __forceinline__ void gload_lds16(const void* g, void* l) {
    __builtin_amdgcn_global_load_lds(
        (const __attribute__((address_space(1))) void*)g,
        (__attribute__((address_space(3))) void*)l, 16, 0, 0);
}

__device__ __forceinline__ void barrier_raw() {
    asm volatile("" ::: "memory");
    __builtin_amdgcn_sched_barrier(0);
    __builtin_amdgcn_s_barrier();
    __builtin_amdgcn_sched_barrier(0);
    asm volatile("" ::: "memory");
}

#define LGKM0()  do { asm volatile("s_waitcnt lgkmcnt(0)" ::: "memory"); \
                      __builtin_amdgcn_sched_barrier(0); } while (0)
#define VMCNT2() do { asm volatile("s_waitcnt vmcnt(2)" ::: "memory"); \
                      __builtin_amdgcn_sched_barrier(0); } while (0)
#define VMCNT0() do { asm volatile("s_waitcnt vmcnt(0)" ::: "memory"); \
                      __builtin_amdgcn_sched_barrier(0); } while (0)

__device__ __forceinline__ float gelu_fast(float v) {
    float w = v * v;
    float z = v * __builtin_fmaf(w, 0.07135481627f, 1.5957691216f);
    float e = __expf(-z);
    return v / (1.0f + e);
}

// ---------------------------------------------------------------------------
// aux kernels
// ---------------------------------------------------------------------------
__global__ __launch_bounds__(256) void absmean_reduce(const float* __restrict__ w,
                                                      double* __restrict__ asum) {
    const int n4 = NW / 4;
    float s = 0.f;
    const float4* w4 = (const float4*)w;
    for (int i = blockIdx.x * blockDim.x + threadIdx.x; i < n4;
         i += gridDim.x * blockDim.x) {
        float4 v = w4[i];
        s += fabsf(v.x) + fabsf(v.y) + fabsf(v.z) + fabsf(v.w);
    }
    #pragma unroll
    for (int off = 32; off > 0; off >>= 1) s += __shfl_down(s, off);
    __shared__ float sm[4];
    int lane = threadIdx.x & 63, wid = threadIdx.x >> 6;
    if (lane == 0) sm[wid] = s;
    __syncthreads();
    if (threadIdx.x == 0) {
        float t = sm[0] + sm[1] + sm[2] + sm[3];
        atomicAdd(asum, (double)t);
    }
}

__global__ __launch_bounds__(256) void quant_kernel(const float* __restrict__ w,
                                                    const double* __restrict__ asum,
                                                    unsigned short* __restrict__ wq) {
    float thr = (float)(0.5 * (*asum) * (1.0 / (double)NW));
    int i = blockIdx.x * blockDim.x + threadIdx.x;
    float4 v = ((const float4*)w)[i];
    ushort4 o;
    o.x = (fabsf(v.x) > thr) ? (v.x > 0.f ? 0x3F80 : 0xBF80) : 0;
    o.y = (fabsf(v.y) > thr) ? (v.y > 0.f ? 0x3F80 : 0xBF80) : 0;
    o.z = (fabsf(v.z) > thr) ? (v.z > 0.f ? 0x3F80 : 0xBF80) : 0;
    o.w = (fabsf(v.w) > thr) ? (v.w > 0.f ? 0x3F80 : 0xBF80) : 0;
    ((ushort4*)wq)[i] = o;
}

__global__ __launch_bounds__(256) void rmsnorm_x(const float* __restrict__ x,
                                                 unsigned short* __restrict__ xn) {
    const int row = blockIdx.x;
    const float4* xr = (const float4*)(x + (size_t)row * D_MODEL);
    float4 v = xr[threadIdx.x];
    float ss = v.x * v.x + v.y * v.y + v.z * v.z + v.w * v.w;
    #pragma unroll
    for (int off = 32; off > 0; off >>= 1) ss += __shfl_down(ss, off);
    __shared__ float sm[4];
    int lane = threadIdx.x & 63, wid = threadIdx.x >> 6;
    if (lane == 0) sm[wid] = ss;
    __syncthreads();
    float tot = sm[0] + sm[1] + sm[2] + sm[3];
    float s = 1.0f / (sqrtf(tot) * (1.0f / 32.0f) + 1e-8f);
    ushort4 o;
    o.x = f2bf(v.x * s); o.y = f2bf(v.y * s);
    o.z = f2bf(v.z * s); o.w = f2bf(v.w * s);
    ((ushort4*)(xn + (size_t)row * D_MODEL))[threadIdx.x] = o;
}

__global__ __launch_bounds__(256) void rowscale_h(const unsigned short* __restrict__ h,
                                                  float* __restrict__ rs) {
    const int row = blockIdx.x;
    const u16x8* hr = (const u16x8*)(h + (size_t)row * D_FF);
    u16x8 a = hr[threadIdx.x * 2 + 0];
    u16x8 b = hr[threadIdx.x * 2 + 1];
    float ss = 0.f;
    #pragma unroll
    for (int j = 0; j < 8; ++j) { float f = bf2f(a[j]); ss += f * f; }
    #pragma unroll
    for (int j = 0; j < 8; ++j) { float f = bf2f(b[j]); ss += f * f; }
    #pragma unroll
    for (int off = 32; off > 0; off >>= 1) ss += __shfl_down(ss, off);
    __shared__ float sm[4];
    int lane = threadIdx.x & 63, wid = threadIdx.x >> 6;
    if (lane == 0) sm[wid] = ss;
    __syncthreads();
    if (threadIdx.x == 0) {
        float tot = sm[0] + sm[1] + sm[2] + sm[3];
        rs[row] = 1.0f / (sqrtf(tot) * (1.0f / 64.0f) + 1e-8f);
    }
}

// ---------------------------------------------------------------------------
// GEMM: C[m][n] = sum_k A[m,k]*B[n,k]   (both K-contiguous)
// BM=BN=256, BK=64, 512 thr (8 waves: 2M x 4N -> 128x64 per wave).
// Phase reads: ph0 = A rows [wm*128, +63] (quarters A0|A2) + all B quarters;
//              ph1 = A rows [wm*128+64, +63] (quarters A1|A3);
//              ph2/ph3 = same rows, kk1 half (no new quarters).
// Stage issue order (tile t+1): ph0 {B0,B1}, ph1 {B2,B3}, ph2 {A0,A2},
// ph3 {A1,A3}. vmcnt(2) at tile end -> B0..B3,A0,A2 resident for ph0;
// vmcnt(2) at end of ph0 -> A1,A3 resident for ph1. Never drains mid-loop.
// ---------------------------------------------------------------------------
template <int EPI, int KDIM, int NBLKN>
__global__ __launch_bounds__(512, 2) void gemm8p(const unsigned short* __restrict__ A,
                                                 const unsigned short* __restrict__ B,
                                                 unsigned short* __restrict__ Cbf,
                                                 float* __restrict__ Cf,
                                                 const float* __restrict__ rowscale,
                                                 int nwg) {
    constexpr int BUFB = 65536;
    constexpr int NT = KDIM / 64;
    __shared__ char smem[2 * BUFB];

    const int tid = threadIdx.x;
    const int bid = blockIdx.x;
    const int swz = (bid & 7) * (nwg >> 3) + (bid >> 3);
    const uint m0 = (uint)(swz / NBLKN) * 256u;
    const uint n0 = (uint)(swz % NBLKN) * 256u;

    const int lane = tid & 63;
    const int wid  = tid >> 6;
    const int wm   = wid >> 2;                  // 0..1 -> 128-row slice
    const int wn   = wid & 3;                   // 0..3 -> 64-col slice
    const int lr   = lane & 15;
    const int lk   = lane >> 4;

    // staging geometry: thread covers row (tid>>3), 16B chunk (tid&7), pre-swizzled
    const uint rowBase = (uint)(tid >> 3);                        // 0..63
    const uint colE = (((uint)(tid & 7) << 4) ^ ((rowBase & 7u) << 4)) >> 1;
    const uint aBase = (m0 + rowBase) * (uint)KDIM + colE;
    const uint bBase = (n0 + rowBase) * (uint)KDIM + colE;
    const uint dstOff = (uint)tid * 16u;

    // fragment read offsets (bytes), same XOR involution as staging
    const uint xorv = ((uint)(lr & 7)) << 4;
    const uint kb0 = (((uint)lk << 4)      ) ^ xorv;
    const uint kb1 = (((uint)lk << 4) | 64u) ^ xorv;
    uint offA[8], offB[4];
    #pragma unroll
    for (int i = 0; i < 8; ++i)
        offA[i] = (uint)(wm * 128 + i * 16 + lr) * 128u;
    #pragma unroll
    for (int i = 0; i < 4; ++i)
        offB[i] = 32768u + (uint)(wn * 64 + i * 16 + lr) * 128u;

    f32x4 acc[8][4];
    #pragma unroll
    for (int mi = 0; mi < 8; ++mi)
        #pragma unroll
        for (int ni = 0; ni < 4; ++ni)
            acc[mi][ni] = (f32x4){0.f, 0.f, 0.f, 0.f};

    // prologue: stage tile 0 in NEED order B0,B1,B2,B3,A0,A2,A1,A3
    {
        char* sb = smem;
        gload_lds16(B + bBase +   0u * KDIM, sb + 32768 +     0 + dstOff);
        gload_lds16(B + bBase +  64u * KDIM, sb + 32768 +  8192 + dstOff);
        gload_lds16(B + bBase + 128u * KDIM, sb + 32768 + 16384 + dstOff);
        gload_lds16(B + bBase + 192u * KDIM, sb + 32768 + 24576 + dstOff);
        gload_lds16(A + aBase +   0u * KDIM, sb +     0 + dstOff);   // A0
        gload_lds16(A + aBase + 128u * KDIM, sb + 16384 + dstOff);   // A2
        gload_lds16(A + aBase +  64u * KDIM, sb +  8192 + dstOff);   // A1
        gload_lds16(A + aBase + 192u * KDIM, sb + 24576 + dstOff);   // A3
    }
    VMCNT2();            // B0..B3, A0, A2 landed; A1, A3 may be in flight
    barrier_raw();

    #pragma unroll 1
    for (int t = 0; t < NT; ++t) {
        const char* cb = smem + (t & 1) * BUFB;
        char* sb = smem + ((t + 1) & 1) * BUFB;
        const uint tOff = (uint)(t + 1) * 64u;
        const bool doStage = (t + 1 < NT);
        bf16x8 av[4], bv0[4], bv1[4];

        // ---- phase 0: acc[0..3] x kk0  (A rows wm*128..+63, all B) ----
        #pragma unroll
        for (int i = 0; i < 4; ++i) av[i]  = *(const bf16x8*)(cb + offA[i] + kb0);
        #pragma unroll
        for (int i = 0; i < 4; ++i) bv0[i] = *(const bf16x8*)(cb + offB[i] + kb0);
        if (doStage) {
            gload_lds16(B + bBase +   0u * KDIM + tOff, sb + 32768 +    0 + dstOff);
            gload_lds16(B + bBase +  64u * KDIM + tOff, sb + 32768 + 8192 + dstOff);
        }
        barrier_raw();
        LGKM0();
        __builtin_amdgcn_s_setprio(1);
        #pragma unroll
        for (int mi = 0; mi < 4; ++mi)
            #pragma unroll
            for (int ni = 0; ni < 4; ++ni)
                acc[mi][ni] = __builtin_amdgcn_mfma_f32_16x16x32_bf16(
                    av[mi], bv0[ni], acc[mi][ni], 0, 0, 0);
        __builtin_amdgcn_s_setprio(0);
        if (doStage) VMCNT2(); else VMCNT0();   // A1(t), A3(t) landed
        barrier_raw();

        // ---- phase 1: acc[4..7] x kk0  (A rows wm*128+64..+127) ----
        #pragma unroll
        for (int i = 0; i < 4; ++i) av[i] = *(const bf16x8*)(cb + offA[4 + i] + kb0);
        if (doStage) {
            gload_lds16(B + bBase + 128u * KDIM + tOff, sb + 32768 + 16384 + dstOff);
            gload_lds16(B + bBase + 192u * KDIM + tOff, sb + 32768 + 24576 + dstOff);
        }
        barrier_raw();
        LGKM0();
        __builtin_amdgcn_s_setprio(1);
        #pragma unroll
        for (int mi = 0; mi < 4; ++mi)
            #pragma unroll
            for (int ni = 0; ni < 4; ++ni)
                acc[4 + mi][ni] = __builtin_amdgcn_mfma_f32_16x16x32_bf16(
                    av[mi], bv0[ni], acc[4 + mi][ni], 0, 0, 0);
        __builtin_amdgcn_s_setprio(0);
        barrier_raw();

        // ---- phase 2: acc[0..3] x kk1 ----
        #pragma unroll
        for (int i = 0; i < 4; ++i) av[i]  = *(const bf16x8*)(cb + offA[i] + kb1);
        #pragma unroll
        for (int i = 0; i < 4; ++i) bv1[i] = *(const bf16x8*)(cb + offB[i] + kb1);
        if (doStage) {
            gload_lds16(A + aBase +   0u * KDIM + tOff, sb +     0 + dstOff);  // A0
            gload_lds16(A + aBase + 128u * KDIM + tOff, sb + 16384 + dstOff);  // A2
        }
        barrier_raw();
        LGKM0();
        __builtin_amdgcn_s_setprio(1);
        #pragma unroll
        for (int mi = 0; mi < 4; ++mi)
            #pragma unroll
            for (int ni = 0; ni < 4; ++ni)
                acc[mi][ni] = __builtin_amdgcn_mfma_f32_16x16x32_bf16(
                    av[mi], bv1[ni], acc[mi][ni], 0, 0, 0);
        __builtin_amdgcn_s_setprio(0);
        barrier_raw();

        // ---- phase 3: acc[4..7] x kk1 ----
        #pragma unroll
        for (int i = 0; i < 4; ++i) av[i] = *(const bf16x8*)(cb + offA[4 + i] + kb1);
        if (doStage) {
            gload_lds16(A + aBase +  64u * KDIM + tOff, sb +  8192 + dstOff);  // A1
            gload_lds16(A + aBase + 192u * KDIM + tOff, sb + 24576 + dstOff);  // A3
        }
        barrier_raw();
        LGKM0();
        __builtin_amdgcn_s_setprio(1);
        #pragma unroll
        for (int mi = 0; mi < 4; ++mi)
            #pragma unroll
            for (int ni = 0; ni < 4; ++ni)
                acc[4 + mi][ni] = __builtin_amdgcn_mfma_f32_16x16x32_bf16(
                    av[mi], bv1[ni], acc[4 + mi][ni], 0, 0, 0);
        __builtin_amdgcn_s_setprio(0);
        if (doStage) VMCNT2(); else VMCNT0();   // B0..B3, A0, A2 of t+1 landed
        barrier_raw();
    }

    // epilogue: C/D frag mapping col = lane&15, row = (lane>>4)*4 + reg
    constexpr uint N = (uint)NBLKN * 256u;
    #pragma unroll
    for (int mi = 0; mi < 8; ++mi) {
        #pragma unroll
        for (int j = 0; j < 4; ++j) {
            const uint gr = m0 + (uint)(wm * 128 + mi * 16 + lk * 4 + j);
            float s = 0.f;
            if (EPI == 1) s = rowscale[gr];
            #pragma unroll
            for (int ni = 0; ni < 4; ++ni) {
                const uint gc = n0 + (uint)(wn * 64 + ni * 16 + lr);
                float v = acc[mi][ni][j];
                if (EPI == 0) {
                    Cbf[gr * N + gc] = f2bf(gelu_fast(v));
                } else {
                    Cf[gr * N + gc] = v * s;
                }
            }
        }
    }
}

// ---------------------------------------------------------------------------
extern "C" void kernel_launch(void* const* d_in, const int* in_sizes, int n_in,
                              void* d_out, int out_size, void* d_ws, size_t ws_size,
                              hipStream_t stream) {
    const float* x    = (const float*)d_in[0];
    const float* w_up = (const float*)d_in[1];
    const float* w_dn = (const float*)d_in[2];
    float* out = (float*)d_out;

    uint8_t* ws = (uint8_t*)d_ws;
    unsigned short* h   = (unsigned short*)(ws);                       // 128 MB
    unsigned short* xn  = (unsigned short*)(ws + 134217728);           // 32 MB
    unsigned short* wqu = (unsigned short*)(ws + 134217728 + 33554432);
    unsigned short* wqd = (unsigned short*)(ws + 134217728 + 33554432 + 8388608);
    float*  rs   = (float*)(ws + 134217728 + 33554432 + 2 * 8388608);
    double* alph = (double*)(ws + 134217728 + 33554432 + 2 * 8388608 + 65536);

    hipMemsetAsync(alph, 0, 16, stream);

    absmean_reduce<<<256, 256, 0, stream>>>(w_up, alph + 0);
    absmean_reduce<<<256, 256, 0, stream>>>(w_dn, alph + 1);
    quant_kernel<<<NW / 1024, 256, 0, stream>>>(w_up, alph + 0, wqu);
    quant_kernel<<<NW / 1024, 256, 0, stream>>>(w_dn, alph + 1, wqd);
    rmsnorm_x<<<M_ROWS, 256, 0, stream>>>(x, xn);

    // L1: h = gelu(xn @ wqu^T)  [16384 x 4096], K=1024 -> 64x16 = 1024 blocks
    gemm8p<0, D_MODEL, 16><<<1024, 512, 0, stream>>>(
        xn, wqu, h, nullptr, nullptr, 1024);

    rowscale_h<<<M_ROWS, 256, 0, stream>>>(h, rs);

    // L2: out = (h @ wqd^T) * rs[m]  [16384 x 1024], K=4096 -> 64x4 = 256 blocks
    gemm8p<1, D_FF, 4><<<256, 512, 0, stream>>>(
        h, wqd, nullptr, out, rs, 256);
}